// Round 5
// baseline (888.481 us; speedup 1.0000x reference)
//
#include <hip/hip_runtime.h>
#include <stdint.h>

// ---------- types ----------
typedef __attribute__((ext_vector_type(8))) short short8;
typedef __attribute__((ext_vector_type(4))) float floatx4;
typedef __attribute__((ext_vector_type(4))) unsigned short ushort4v;

__device__ inline float bf2f(unsigned short u) {
  union { unsigned int i; float f; } v; v.i = ((unsigned int)u) << 16; return v.f;
}
__device__ inline unsigned short f2bf(float f) {
  union { float f; unsigned int i; } v; v.f = f;
  unsigned int r = v.i + 0x7FFFu + ((v.i >> 16) & 1u);  // round-nearest-even
  return (unsigned short)(r >> 16);
}

// ---------- utility ----------
__global__ void zero_i32(int* __restrict__ p, int n) {
  int i = blockIdx.x * blockDim.x + threadIdx.x;
  if (i < n) p[i] = 0;
}

// x fp32 -> bf16 (vectorized, 4 elems/thread)
__global__ void conv_x(const float* __restrict__ X, unsigned short* __restrict__ xb, int n4) {
  int i = blockIdx.x * blockDim.x + threadIdx.x;
  if (i < n4) {
    float4 v = *(const float4*)&X[i * 4];
    ushort4v o = { f2bf(v.x), f2bf(v.y), f2bf(v.z), f2bf(v.w) };
    *(ushort4v*)&xb[i * 4] = o;
  }
}

// ---- CSR build, pass 1: per-(dst,rel) histogram; atomic return value IS the
//      edge's rank within its bin (order nondeterministic, but we only sum). ----
__global__ void count_rank(const int* __restrict__ dst, const int* __restrict__ et,
                           int* __restrict__ cnt, unsigned short* __restrict__ rank,
                           int E) {
  int e = blockIdx.x * blockDim.x + threadIdx.x;
  if (e < E) {
    int idx = dst[e] * 8 + et[e];
    rank[e] = (unsigned short)atomicAdd(&cnt[idx], 1);
  }
}

// inv[i] = 1/max(cnt[i],1)  (mean weights)
__global__ void invert_cnt(const int* __restrict__ cnt, float* __restrict__ inv, int n) {
  int i = blockIdx.x * blockDim.x + threadIdx.x;
  if (i < n) inv[i] = 1.0f / fmaxf((float)cnt[i], 1.0f);
}

// ---------- exclusive scan of cnt[n2] -> eptr8[n2] (+eptr8[n2]=E) ----------
#define SCAN_T 256
#define SCAN_E 4   // 1024 elems per block

__global__ void scan1(const int* __restrict__ cnt, int* __restrict__ bsum, int n) {
  __shared__ int lds[SCAN_T];
  int base = blockIdx.x * (SCAN_T * SCAN_E);
  int tid = threadIdx.x;
  int s = 0;
#pragma unroll
  for (int j = 0; j < SCAN_E; ++j) {
    int i = base + tid * SCAN_E + j;
    if (i < n) s += cnt[i];
  }
  lds[tid] = s; __syncthreads();
  for (int off = SCAN_T / 2; off > 0; off >>= 1) {
    if (tid < off) lds[tid] += lds[tid + off];
    __syncthreads();
  }
  if (tid == 0) bsum[blockIdx.x] = lds[0];
}

__global__ void scan2(int* __restrict__ bsum, int* __restrict__ eptr, int nb, int n) {
  __shared__ int lds[SCAN_T];
  int tid = threadIdx.x;
  int loc[4]; int s = 0;
#pragma unroll
  for (int j = 0; j < 4; ++j) {
    int i = tid * 4 + j;
    loc[j] = (i < nb) ? bsum[i] : 0; s += loc[j];
  }
  lds[tid] = s; __syncthreads();
  for (int off = 1; off < SCAN_T; off <<= 1) {   // Hillis-Steele inclusive
    int v = (tid >= off) ? lds[tid - off] : 0;
    __syncthreads();
    lds[tid] += v;
    __syncthreads();
  }
  int run = (tid > 0 ? lds[tid - 1] : 0);
#pragma unroll
  for (int j = 0; j < 4; ++j) {
    int i = tid * 4 + j;
    if (i < nb) { int v = loc[j]; bsum[i] = run; run += v; }
  }
  if (tid == 0) eptr[n] = lds[SCAN_T - 1];   // total = E
}

__global__ void scan3(const int* __restrict__ cnt, const int* __restrict__ bsum,
                      int* __restrict__ eptr, int n) {
  __shared__ int lds[SCAN_T];
  int base = blockIdx.x * (SCAN_T * SCAN_E);
  int tid = threadIdx.x;
  int loc[SCAN_E]; int s = 0;
#pragma unroll
  for (int j = 0; j < SCAN_E; ++j) {
    int i = base + tid * SCAN_E + j;
    loc[j] = (i < n) ? cnt[i] : 0; s += loc[j];
  }
  lds[tid] = s; __syncthreads();
  for (int off = 1; off < SCAN_T; off <<= 1) {
    int v = (tid >= off) ? lds[tid - off] : 0;
    __syncthreads();
    lds[tid] += v;
    __syncthreads();
  }
  int run = (tid > 0 ? lds[tid - 1] : 0) + bsum[blockIdx.x];
#pragma unroll
  for (int j = 0; j < SCAN_E; ++j) {
    int i = base + tid * SCAN_E + j;
    if (i < n) { eptr[i] = run; run += loc[j]; }
  }
}

// ---- CSR build, pass 2: deterministic placement, NO atomics.
//      position = eptr8[d*8+r] + rank[e]; entry = src (rel implied by bin) ----
__global__ void scatter_edges(const int* __restrict__ src, const int* __restrict__ dst,
                              const int* __restrict__ et, const int* __restrict__ eptr8,
                              const unsigned short* __restrict__ rank,
                              unsigned* __restrict__ entry, int E) {
  int e = blockIdx.x * blockDim.x + threadIdx.x;
  if (e < E) {
    int d = dst[e], r = et[e];
    int p = eptr8[d * 8 + r] + (int)rank[e];
    entry[p] = (unsigned)src[e];
  }
}

// ---------- weight prep: all 9 matrices (8 W + root) -> bf16, MFMA-fragment-
// swizzled layout: Wb[m][ ((kc*4+q)*4+nt)*16+lc ][j],  k=kc*32+q*8+j, c=nt*16+lc
__global__ void conv_weights(const float* __restrict__ W, const float* __restrict__ root,
                             unsigned short* __restrict__ Wb, int R) {
  int i = blockIdx.x * blockDim.x + threadIdx.x;
  int total = (R + 1) * 4096;
  if (i >= total) return;
  int m = i >> 12, rem = i & 4095, k = rem >> 6, c = rem & 63;
  float w = (m < R) ? W[(size_t)m * 4096 + k * 64 + c] : root[(size_t)k * 64 + c];
  int kc = k >> 5, q = (k >> 3) & 3, j = k & 7, nt = c >> 4, lcv = c & 15;
  Wb[(size_t)m * 4096 + (size_t)(((kc * 4 + q) * 4 + nt) * 16 + lcv) * 8 + j] = f2bf(w);
}

// ---------- fused aggregate-then-transform RGCN layer.
// One wave owns 16 dst nodes; lane = feature dim. CSR is rel-sorted per node, so
// per-(d,rel) sums are contiguous ranges: per k-half (rels h*4..h*4+3) walk the
// node's 4 bins as 4 INTERLEAVED register chains (uniform branches, 4-deep MLP),
// scale by inv, f2bf, store to the XOR-swizzled A-tile; then 8 kc-steps of
// MFMA 16x16x32 with B-frags from global Wb (L1/L2-hot). Root + bias in epilogue.
// mode=1: out = hb bf16 relu (layer 1);  mode=0: out = acc fp32 (layer 2).
//
// A-tile layout (per wave, 16 rows x 256 k, bf16): element (row,k):
//   f=k>>3, j=k&7 -> idx = f*128 + ((row*8) ^ ((f&7)*16)) + j   (bijective <4096)
//   writer (node ni, rel r, lane=c): f=r*8+(c>>3) ->
//     idx = (c>>3)*128+(c&7) + r*1024 + ((ni*8)^((c>>3)*16))
//   reader (kc, lane): f=kc*4+quad ->
//     idx = (kc*4+quad)*128 + ((lc*8) ^ (((kc&1)*4+quad)*16))   (ds_read_b128)
// both sides <=2-way bank aliasing (free). No __syncthreads (waves independent).
__global__ void __launch_bounds__(256)
rgcn_fused(const unsigned short* __restrict__ xb, const unsigned short* __restrict__ Wb,
           const float* __restrict__ bias, const int* __restrict__ eptr8,
           const unsigned* __restrict__ entry, const float* __restrict__ inv,
           unsigned short* __restrict__ hb, float* __restrict__ acc,
           int N, int mode)
{
  __shared__ __align__(16) unsigned short atile[4 * 4096];  // 32 KB -> 5 blocks/CU

  const int lane = threadIdx.x & 63;
  const int wave = threadIdx.x >> 6;
  const int lc   = lane & 15;
  const int quad = lane >> 4;
  const int tiles = (N + 15) >> 4;
  const int t = blockIdx.x * 4 + wave;
  if (t >= tiles) return;
  const int nb = t << 4;

  const int aw    = wave * 4096;
  const int wbase = aw + ((lane >> 3) * 128) + (lane & 7);
  const int wx    = (lane >> 3) * 16;

  floatx4 dacc[4];
#pragma unroll
  for (int nt = 0; nt < 4; ++nt) dacc[nt] = (floatx4){0.f, 0.f, 0.f, 0.f};

  for (int h = 0; h < 2; ++h) {
    const int h4 = h * 4;
    // ---- aggregation: 16 nodes x 4 rel-bins -> swizzled A-tile ----
    for (int ni = 0; ni < 16; ++ni) {
      const int d = nb + ni;
      const int base = d * 8 + h4;
      const int b0 = eptr8[base],     b1 = eptr8[base + 1];
      const int b2 = eptr8[base + 2], b3 = eptr8[base + 3], b4 = eptr8[base + 4];
      const float4 iq = *(const float4*)&inv[base];   // uniform 16B load
      float s0 = 0.f, s1 = 0.f, s2 = 0.f, s3 = 0.f;
      int e0 = b0, e1 = b1, e2 = b2, e3 = b3;
      // 4 interleaved independent chains (all control uniform across the wave)
      while ((e0 < b1) | (e1 < b2) | (e2 < b3) | (e3 < b4)) {
        if (e0 < b1) s0 += bf2f(xb[(size_t)entry[e0++] * 64 + lane]);
        if (e1 < b2) s1 += bf2f(xb[(size_t)entry[e1++] * 64 + lane]);
        if (e2 < b3) s2 += bf2f(xb[(size_t)entry[e2++] * 64 + lane]);
        if (e3 < b4) s3 += bf2f(xb[(size_t)entry[e3++] * 64 + lane]);
      }
      const int wsl = wbase + ((ni * 8) ^ wx);
      atile[wsl]        = f2bf(s0 * iq.x);
      atile[wsl + 1024] = f2bf(s1 * iq.y);
      atile[wsl + 2048] = f2bf(s2 * iq.z);
      atile[wsl + 3072] = f2bf(s3 * iq.w);
    }
    // ---- MFMA over this half (k = 256: rels h4..h4+3) ----
#pragma unroll
    for (int kc = 0; kc < 8; ++kc) {
      const int m = h4 + (kc >> 1);
      const short8 af = *(const short8*)&atile[aw + (kc * 4 + quad) * 128 +
                                               ((lc * 8) ^ (((kc & 1) * 4 + quad) * 16))];
#pragma unroll
      for (int nt = 0; nt < 4; ++nt) {
        const short8 bf = *(const short8*)&Wb[(size_t)m * 4096 +
            (size_t)((((kc & 1) * 4 + quad) * 4 + nt) * 16 + lc) * 8];
        dacc[nt] = __builtin_amdgcn_mfma_f32_16x16x32_bf16(af, bf, dacc[nt], 0, 0, 0);
      }
    }
  }
  // ---- root term: A-frags straight from xb rows ----
  {
    const int row = min(nb + lc, N - 1);
#pragma unroll
    for (int kc2 = 0; kc2 < 2; ++kc2) {
      const short8 af = *(const short8*)&xb[(size_t)row * 64 + kc2 * 32 + quad * 8];
#pragma unroll
      for (int nt = 0; nt < 4; ++nt) {
        const short8 bf = *(const short8*)&Wb[(size_t)8 * 4096 +
            (size_t)(((kc2 * 4 + quad) * 4 + nt) * 16 + lc) * 8];
        dacc[nt] = __builtin_amdgcn_mfma_f32_16x16x32_bf16(af, bf, dacc[nt], 0, 0, 0);
      }
    }
  }
  // ---- epilogue: + bias; mode1 -> relu+bf16 (layer-2 input), mode0 -> fp32 acc ----
#pragma unroll
  for (int nt = 0; nt < 4; ++nt) {
    const int c = nt * 16 + lc;
    const float bv = bias[c];
    if (mode) {
#pragma unroll
      for (int i = 0; i < 4; ++i) {
        int r_ = nb + quad * 4 + i;
        if (r_ < N) hb[(size_t)r_ * 64 + c] = f2bf(fmaxf(dacc[nt][i] + bv, 0.f));
      }
    } else {
#pragma unroll
      for (int i = 0; i < 4; ++i) {
        int r_ = nb + quad * 4 + i;
        if (r_ < N) acc[(size_t)r_ * 64 + c] = dacc[nt][i] + bv;
      }
    }
  }
}

// graph segment boundaries from sorted batch: glo[g] = lower_bound(batch, g); glo[G]=N
__global__ void glo_bounds(const int* __restrict__ batch, int* __restrict__ glo,
                           int N, int G) {
  int g = blockIdx.x * blockDim.x + threadIdx.x;
  if (g > G) return;
  if (g == G) { glo[G] = N; return; }
  int lo = 0, hi = N;
  while (lo < hi) { int mid = (lo + hi) >> 1; if (batch[mid] < g) lo = mid + 1; else hi = mid; }
  glo[g] = lo;
}

// ---------- mean pool, stage 1 ----------
#define PS 24
__global__ void __launch_bounds__(256)
pool1(const float* __restrict__ acc, const int* __restrict__ glo,
      float* __restrict__ partial, int G)
{
  const int g = blockIdx.x;
  const int s = blockIdx.y;
  const int lane = threadIdx.x & 63;
  const int w = threadIdx.x >> 6;
  const int lo = glo[g], hi = glo[g + 1];
  const int len = hi - lo;
  const int a = lo + (int)(((long long)len * s) / PS);
  const int b = lo + (int)(((long long)len * (s + 1)) / PS);
  float sum = 0.f;
  for (int n = a + w; n < b; n += 4) sum += acc[(size_t)n * 64 + lane];
  __shared__ float red[4][64];
  red[w][lane] = sum;
  __syncthreads();
  if (w == 0)
    partial[((size_t)g * PS + s) * 64 + lane] =
        red[0][lane] + red[1][lane] + red[2][lane] + red[3][lane];
}

__global__ void pool2(const float* __restrict__ partial, const int* __restrict__ glo,
                      float* __restrict__ out, int G)
{
  const int g = blockIdx.x;
  const int lane = threadIdx.x;   // 64 threads
  float t = 0.f;
#pragma unroll
  for (int s = 0; s < PS; ++s) t += partial[((size_t)g * PS + s) * 64 + lane];
  const int len = glo[g + 1] - glo[g];
  out[(size_t)g * 64 + lane] = t / fmaxf((float)len, 1.0f);
}

// ---------- launch ----------
extern "C" void kernel_launch(void* const* d_in, const int* in_sizes, int n_in,
                              void* d_out, int out_size, void* d_ws, size_t ws_size,
                              hipStream_t stream)
{
  const float* x     = (const float*)d_in[0];
  const int*   ei    = (const int*)d_in[1];
  const int*   etype = (const int*)d_in[2];
  const int*   batch = (const int*)d_in[3];
  const float* W1    = (const float*)d_in[4];
  const float* root1 = (const float*)d_in[5];
  const float* b1    = (const float*)d_in[6];
  const float* W2    = (const float*)d_in[7];
  const float* root2 = (const float*)d_in[8];
  const float* b2    = (const float*)d_in[9];

  const int N = in_sizes[0] / 64;
  const int E = in_sizes[1] / 2;
  const int R = in_sizes[4] / (64 * 64);   // == 8
  const int G = out_size / 64;
  const int* srcp = ei;
  const int* dstp = ei + E;
  const int n2 = N * R;   // (dst,rel) bins

  // workspace carve-up (256B aligned), ~71 MB total — no aliasing
  char* ws = (char*)d_ws;
  size_t off = 0;
  auto carve = [&](size_t bytes) -> void* {
    void* p = ws + off; off = (off + bytes + 255) & ~(size_t)255; return p;
  };
  float*          inv     = (float*)carve((size_t)n2 * 4);
  unsigned short* xb      = (unsigned short*)carve((size_t)N * 64 * 2);
  unsigned short* hb      = (unsigned short*)carve((size_t)N * 64 * 2);
  float*          acc     = (float*)carve((size_t)N * 64 * 4);
  int*            eptr8   = (int*)carve((size_t)(n2 + 1) * 4);
  unsigned*       entry   = (unsigned*)carve((size_t)E * 4);
  unsigned short* rank    = (unsigned short*)carve((size_t)E * 2);
  int*            cnt     = (int*)carve((size_t)n2 * 4);
  int*            bsum    = (int*)carve(1024 * 4);
  int*            glo     = (int*)carve((size_t)(G + 1) * 4);
  float*          partial = (float*)carve((size_t)G * PS * 64 * 4);
  unsigned short* Wb      = (unsigned short*)carve((size_t)(R + 1) * 4096 * 2);
  (void)ws_size; (void)n_in;

  const int nb2 = (n2 + SCAN_T * SCAN_E - 1) / (SCAN_T * SCAN_E);

  // ---- CSR build: 1 atomic per edge total ----
  zero_i32<<<(n2 + 255) / 256, 256, 0, stream>>>(cnt, n2);
  count_rank<<<(E + 255) / 256, 256, 0, stream>>>(dstp, etype, cnt, rank, E);
  invert_cnt<<<(n2 + 255) / 256, 256, 0, stream>>>(cnt, inv, n2);
  scan1<<<nb2, SCAN_T, 0, stream>>>(cnt, bsum, n2);
  scan2<<<1, SCAN_T, 0, stream>>>(bsum, eptr8, nb2, n2);
  scan3<<<nb2, SCAN_T, 0, stream>>>(cnt, bsum, eptr8, n2);
  scatter_edges<<<(E + 255) / 256, 256, 0, stream>>>(srcp, dstp, etype, eptr8, rank, entry, E);

  const int tiles = (N + 15) >> 4;
  const int fblocks = (tiles + 3) / 4;
  const int wblocks = ((R + 1) * 4096 + 255) / 256;

  // ---- input to bf16 ----
  conv_x<<<(N * 64 / 4 + 255) / 256, 256, 0, stream>>>(x, xb, N * 64 / 4);

  // ---- layer 1 (out: hb = relu bf16) ----
  conv_weights<<<wblocks, 256, 0, stream>>>(W1, root1, Wb, R);
  rgcn_fused<<<fblocks, 256, 0, stream>>>(xb, Wb, b1, eptr8, entry, inv, hb, nullptr, N, 1);

  // ---- layer 2 (out: acc fp32) ----
  conv_weights<<<wblocks, 256, 0, stream>>>(W2, root2, Wb, R);
  rgcn_fused<<<fblocks, 256, 0, stream>>>(hb, Wb, b2, eptr8, entry, inv, nullptr, acc, N, 0);

  // ---- global mean pool (two-stage, parallel) ----
  glo_bounds<<<1, 128, 0, stream>>>(batch, glo, N, G);
  dim3 pgrid(G, PS);
  pool1<<<pgrid, 256, 0, stream>>>(acc, glo, partial, G);
  pool2<<<G, 64, 0, stream>>>(partial, glo, (float*)d_out, G);
}

// Round 6
// 433.596 us; speedup vs baseline: 2.0491x; 2.0491x over previous
//
#include <hip/hip_runtime.h>
#include <stdint.h>

// ---------- types ----------
typedef __attribute__((ext_vector_type(8))) short short8;
typedef __attribute__((ext_vector_type(4))) float floatx4;

__device__ inline float bf2f(unsigned short u) {
  union { unsigned int i; float f; } v; v.i = ((unsigned int)u) << 16; return v.f;
}
__device__ inline unsigned short f2bf(float f) {
  union { float f; unsigned int i; } v; v.f = f;
  unsigned int r = v.i + 0x7FFFu + ((v.i >> 16) & 1u);  // round-nearest-even
  return (unsigned short)(r >> 16);
}

// ---------- utility ----------
__global__ void zero_i32(int* __restrict__ p, int n) {
  int i = blockIdx.x * blockDim.x + threadIdx.x;
  if (i < n) p[i] = 0;
}

// ---- CSR build, pass 1: per-(dst,rel) histogram; atomic return value IS the
//      edge's rank within its bin (order nondeterministic, but we only sum). ----
__global__ void count_rank(const int* __restrict__ dst, const int* __restrict__ et,
                           int* __restrict__ cnt, unsigned short* __restrict__ rank,
                           int E) {
  int e = blockIdx.x * blockDim.x + threadIdx.x;
  if (e < E) {
    int idx = dst[e] * 8 + et[e];
    rank[e] = (unsigned short)atomicAdd(&cnt[idx], 1);
  }
}

// inv[i] = 1/max(cnt[i],1)  (mean weights)
__global__ void invert_cnt(const int* __restrict__ cnt, float* __restrict__ inv, int n) {
  int i = blockIdx.x * blockDim.x + threadIdx.x;
  if (i < n) inv[i] = 1.0f / fmaxf((float)cnt[i], 1.0f);
}

// ---------- exclusive scan of cnt[n2] -> eptr8[n2] (+eptr8[n2]=E) ----------
#define SCAN_T 256
#define SCAN_E 4   // 1024 elems per block

__global__ void scan1(const int* __restrict__ cnt, int* __restrict__ bsum, int n) {
  __shared__ int lds[SCAN_T];
  int base = blockIdx.x * (SCAN_T * SCAN_E);
  int tid = threadIdx.x;
  int s = 0;
#pragma unroll
  for (int j = 0; j < SCAN_E; ++j) {
    int i = base + tid * SCAN_E + j;
    if (i < n) s += cnt[i];
  }
  lds[tid] = s; __syncthreads();
  for (int off = SCAN_T / 2; off > 0; off >>= 1) {
    if (tid < off) lds[tid] += lds[tid + off];
    __syncthreads();
  }
  if (tid == 0) bsum[blockIdx.x] = lds[0];
}

__global__ void scan2(int* __restrict__ bsum, int* __restrict__ eptr, int nb, int n) {
  __shared__ int lds[SCAN_T];
  int tid = threadIdx.x;
  int loc[4]; int s = 0;
#pragma unroll
  for (int j = 0; j < 4; ++j) {
    int i = tid * 4 + j;
    loc[j] = (i < nb) ? bsum[i] : 0; s += loc[j];
  }
  lds[tid] = s; __syncthreads();
  for (int off = 1; off < SCAN_T; off <<= 1) {   // Hillis-Steele inclusive
    int v = (tid >= off) ? lds[tid - off] : 0;
    __syncthreads();
    lds[tid] += v;
    __syncthreads();
  }
  int run = (tid > 0 ? lds[tid - 1] : 0);
#pragma unroll
  for (int j = 0; j < 4; ++j) {
    int i = tid * 4 + j;
    if (i < nb) { int v = loc[j]; bsum[i] = run; run += v; }
  }
  if (tid == 0) eptr[n] = lds[SCAN_T - 1];   // total = E
}

__global__ void scan3(const int* __restrict__ cnt, const int* __restrict__ bsum,
                      int* __restrict__ eptr, int n) {
  __shared__ int lds[SCAN_T];
  int base = blockIdx.x * (SCAN_T * SCAN_E);
  int tid = threadIdx.x;
  int loc[SCAN_E]; int s = 0;
#pragma unroll
  for (int j = 0; j < SCAN_E; ++j) {
    int i = base + tid * SCAN_E + j;
    loc[j] = (i < n) ? cnt[i] : 0; s += loc[j];
  }
  lds[tid] = s; __syncthreads();
  for (int off = 1; off < SCAN_T; off <<= 1) {
    int v = (tid >= off) ? lds[tid - off] : 0;
    __syncthreads();
    lds[tid] += v;
    __syncthreads();
  }
  int run = (tid > 0 ? lds[tid - 1] : 0) + bsum[blockIdx.x];
#pragma unroll
  for (int j = 0; j < SCAN_E; ++j) {
    int i = base + tid * SCAN_E + j;
    if (i < n) { eptr[i] = run; run += loc[j]; }
  }
}

// ---- CSR build, pass 2: deterministic placement, NO atomics.
//      position = eptr8[d*8+r] + rank[e]; entry = (src<<3)|rel ----
__global__ void scatter_edges(const int* __restrict__ src, const int* __restrict__ dst,
                              const int* __restrict__ et, const int* __restrict__ eptr8,
                              const unsigned short* __restrict__ rank,
                              unsigned* __restrict__ entry, int E) {
  int e = blockIdx.x * blockDim.x + threadIdx.x;
  if (e < E) {
    int d = dst[e], r = et[e];
    int p = eptr8[d * 8 + r] + (int)rank[e];
    entry[p] = ((unsigned)src[e] << 3) | (unsigned)r;
  }
}

// ---------- weight prep: all 9 matrices (8 W + root) -> bf16, MFMA-fragment-
// swizzled layout so transform reads each lane's 8-elem fragment as one
// ds_read_b128: Wb[m][ ((kc*4+q)*4+nt)*16+lc ][j],  k=kc*32+q*8+j, c=nt*16+lc
__global__ void conv_weights(const float* __restrict__ W, const float* __restrict__ root,
                             unsigned short* __restrict__ Wb, int R) {
  int i = blockIdx.x * blockDim.x + threadIdx.x;
  int total = (R + 1) * 4096;
  if (i >= total) return;
  int m = i >> 12, rem = i & 4095, k = rem >> 6, c = rem & 63;
  float w = (m < R) ? W[(size_t)m * 4096 + k * 64 + c] : root[(size_t)k * 64 + c];
  int kc = k >> 5, q = (k >> 3) & 3, j = k & 7, nt = c >> 4, lcv = c & 15;
  Wb[(size_t)m * 4096 + (size_t)(((kc * 4 + q) * 4 + nt) * 16 + lcv) * 8 + j] = f2bf(w);
}

// ---------- fused transform: each block stages a slice of weight matrices in LDS,
// loads+converts each A-tile ONCE, loops groups inside.
//   y=0: groups 0..3 (W0-3, 32KB LDS)   y=1: groups 4..8 (W4-7 + root, 40KB LDS)
// Y[n][g*64+c] = sum_d act(X[n][d]) * W_g[d][c]   (g<8, bf16 out)
// acc[n][c]    = b[c] + sum_d act(X[n][d]) * root[d][c]  (g==8)
__global__ void __launch_bounds__(256)
transform_fused(const float* __restrict__ X, const unsigned short* __restrict__ Wb,
                const float* __restrict__ bias, unsigned short* __restrict__ Y,
                float* __restrict__ acc, int N, int relu_in)
{
  const int gy   = blockIdx.y;
  const int base = gy ? 4 : 0;
  const int ng   = gy ? 5 : 4;
  __shared__ __align__(16) unsigned short wlds[5 * 4096];   // 40 KB -> 4 blocks/CU

  // cooperative stage: ng*4096 ushorts, 16B chunks (exact multiple of 256 threads)
  const unsigned short* wsrc = Wb + (size_t)base * 4096;
  const int nel = ng * 4096;
  for (int i = threadIdx.x * 8; i < nel; i += 256 * 8)
    *(uint4*)&wlds[i] = *(const uint4*)&wsrc[i];
  __syncthreads();

  const int lane = threadIdx.x & 63;
  const int wave = threadIdx.x >> 6;
  const int lc   = lane & 15;
  const int quad = lane >> 4;
  const int tiles  = (N + 15) >> 4;
  const int stride = gridDim.x * 4;

  for (int t = blockIdx.x * 4 + wave; t < tiles; t += stride) {
    const int nb  = t << 4;
    const int row = min(nb + lc, N - 1);
    const float* xr = X + (size_t)row * 64;
    short8 a0, a1;
#pragma unroll
    for (int j = 0; j < 8; ++j) {
      float v0 = xr[quad * 8 + j];
      float v1 = xr[32 + quad * 8 + j];
      if (relu_in) { v0 = fmaxf(v0, 0.f); v1 = fmaxf(v1, 0.f); }
      a0[j] = (short)f2bf(v0);
      a1[j] = (short)f2bf(v1);
    }
    for (int gi = 0; gi < ng; ++gi) {
      const int g = base + gi;
#pragma unroll
      for (int nt = 0; nt < 4; ++nt) {
        short8 b0 = *(const short8*)&wlds[gi * 4096 + (((0 * 4 + quad) * 4 + nt) * 16 + lc) * 8];
        short8 b1 = *(const short8*)&wlds[gi * 4096 + (((1 * 4 + quad) * 4 + nt) * 16 + lc) * 8];
        floatx4 d = {0.f, 0.f, 0.f, 0.f};
        d = __builtin_amdgcn_mfma_f32_16x16x32_bf16(a0, b0, d, 0, 0, 0);
        d = __builtin_amdgcn_mfma_f32_16x16x32_bf16(a1, b1, d, 0, 0, 0);
        const int c = nt * 16 + lc;
        if (g < 8) {
#pragma unroll
          for (int i = 0; i < 4; ++i) {
            int r_ = nb + quad * 4 + i;
            if (r_ < N) Y[(size_t)r_ * 512 + g * 64 + c] = f2bf(d[i]);
          }
        } else {
          float bv = bias[c];
#pragma unroll
          for (int i = 0; i < 4; ++i) {
            int r_ = nb + quad * 4 + i;
            if (r_ < N) acc[(size_t)r_ * 64 + c] = d[i] + bv;
          }
        }
      }
    }
  }
}

// ---------- CSR edge aggregation: one wave per dst node, no atomics.
// acc[d][lane] += sum_{e in seg(d)} Y[src_e][rel_e*64+lane] * inv[d*8+rel_e]
// Edge indices are prefetched 64-at-a-time with ONE coalesced load, then
// broadcast via __shfl (VALU) — so the Y-gathers form a stream of INDEPENDENT
// loads the compiler can keep 8+ deep in flight (no entry->Y dependent chain).
__global__ void __launch_bounds__(256)
edge_agg_csr(const unsigned short* __restrict__ Y, const int* __restrict__ eptr8,
             const unsigned* __restrict__ entry, const float* __restrict__ inv,
             float* __restrict__ acc, int N)
{
  const int wid  = (blockIdx.x * blockDim.x + threadIdx.x) >> 6;
  const int lane = threadIdx.x & 63;
  if (wid >= N) return;
  const int lo = eptr8[wid * 8], hi = eptr8[wid * 8 + 8];
  const float invv = inv[(size_t)wid * 8 + (lane & 7)];   // lanes 0..7 hold the 8 rel weights
  float sum = 0.f;
  for (int base = lo; base < hi; base += 64) {
    const int rem = hi - base;
    const int mm = rem < 64 ? rem : 64;
    // one coalesced prefetch of up to 64 edge records
    const unsigned en = entry[base + (lane < mm ? lane : mm - 1)];
    int j = 0;
    for (; j + 8 <= mm; j += 8) {
      unsigned e0 = __shfl(en, j),     e1 = __shfl(en, j + 1);
      unsigned e2 = __shfl(en, j + 2), e3 = __shfl(en, j + 3);
      unsigned e4 = __shfl(en, j + 4), e5 = __shfl(en, j + 5);
      unsigned e6 = __shfl(en, j + 6), e7 = __shfl(en, j + 7);
      float v0 = bf2f(Y[(size_t)(e0 >> 3) * 512 + (e0 & 7) * 64 + lane]);
      float v1 = bf2f(Y[(size_t)(e1 >> 3) * 512 + (e1 & 7) * 64 + lane]);
      float v2 = bf2f(Y[(size_t)(e2 >> 3) * 512 + (e2 & 7) * 64 + lane]);
      float v3 = bf2f(Y[(size_t)(e3 >> 3) * 512 + (e3 & 7) * 64 + lane]);
      float v4 = bf2f(Y[(size_t)(e4 >> 3) * 512 + (e4 & 7) * 64 + lane]);
      float v5 = bf2f(Y[(size_t)(e5 >> 3) * 512 + (e5 & 7) * 64 + lane]);
      float v6 = bf2f(Y[(size_t)(e6 >> 3) * 512 + (e6 & 7) * 64 + lane]);
      float v7 = bf2f(Y[(size_t)(e7 >> 3) * 512 + (e7 & 7) * 64 + lane]);
      sum += v0 * __shfl(invv, (int)(e0 & 7)) + v1 * __shfl(invv, (int)(e1 & 7))
           + v2 * __shfl(invv, (int)(e2 & 7)) + v3 * __shfl(invv, (int)(e3 & 7))
           + v4 * __shfl(invv, (int)(e4 & 7)) + v5 * __shfl(invv, (int)(e5 & 7))
           + v6 * __shfl(invv, (int)(e6 & 7)) + v7 * __shfl(invv, (int)(e7 & 7));
    }
    for (; j < mm; ++j) {
      unsigned e0 = __shfl(en, j);
      float v = bf2f(Y[(size_t)(e0 >> 3) * 512 + (e0 & 7) * 64 + lane]);
      sum += v * __shfl(invv, (int)(e0 & 7));
    }
  }
  acc[(size_t)wid * 64 + lane] += sum;
}

// graph segment boundaries from sorted batch: glo[g] = lower_bound(batch, g); glo[G]=N
__global__ void glo_bounds(const int* __restrict__ batch, int* __restrict__ glo,
                           int N, int G) {
  int g = blockIdx.x * blockDim.x + threadIdx.x;
  if (g > G) return;
  if (g == G) { glo[G] = N; return; }
  int lo = 0, hi = N;
  while (lo < hi) { int mid = (lo + hi) >> 1; if (batch[mid] < g) lo = mid + 1; else hi = mid; }
  glo[g] = lo;
}

// ---------- mean pool, stage 1: (G x PS) grid, each block sums one slice of one
// graph's contiguous node segment into partial[g][s][64]. Deterministic, no atomics.
#define PS 24
__global__ void __launch_bounds__(256)
pool1(const float* __restrict__ acc, const int* __restrict__ glo,
      float* __restrict__ partial, int G)
{
  const int g = blockIdx.x;
  const int s = blockIdx.y;
  const int lane = threadIdx.x & 63;
  const int w = threadIdx.x >> 6;
  const int lo = glo[g], hi = glo[g + 1];
  const int len = hi - lo;
  const int a = lo + (int)(((long long)len * s) / PS);
  const int b = lo + (int)(((long long)len * (s + 1)) / PS);
  float sum = 0.f;
  for (int n = a + w; n < b; n += 4) sum += acc[(size_t)n * 64 + lane];
  __shared__ float red[4][64];
  red[w][lane] = sum;
  __syncthreads();
  if (w == 0)
    partial[((size_t)g * PS + s) * 64 + lane] =
        red[0][lane] + red[1][lane] + red[2][lane] + red[3][lane];
}

// stage 2: reduce PS slices, divide by segment length
__global__ void pool2(const float* __restrict__ partial, const int* __restrict__ glo,
                      float* __restrict__ out, int G)
{
  const int g = blockIdx.x;
  const int lane = threadIdx.x;   // 64 threads
  float t = 0.f;
#pragma unroll
  for (int s = 0; s < PS; ++s) t += partial[((size_t)g * PS + s) * 64 + lane];
  const int len = glo[g + 1] - glo[g];
  out[(size_t)g * 64 + lane] = t / fmaxf((float)len, 1.0f);
}

// ---------- launch ----------
extern "C" void kernel_launch(void* const* d_in, const int* in_sizes, int n_in,
                              void* d_out, int out_size, void* d_ws, size_t ws_size,
                              hipStream_t stream)
{
  const float* x     = (const float*)d_in[0];
  const int*   ei    = (const int*)d_in[1];
  const int*   etype = (const int*)d_in[2];
  const int*   batch = (const int*)d_in[3];
  const float* W1    = (const float*)d_in[4];
  const float* root1 = (const float*)d_in[5];
  const float* b1    = (const float*)d_in[6];
  const float* W2    = (const float*)d_in[7];
  const float* root2 = (const float*)d_in[8];
  const float* b2    = (const float*)d_in[9];

  const int N = in_sizes[0] / 64;
  const int E = in_sizes[1] / 2;
  const int R = in_sizes[4] / (64 * 64);   // == 8
  const int G = out_size / 64;
  const int* srcp = ei;
  const int* dstp = ei + E;
  const int n2 = N * R;   // (dst,rel) bins

  // workspace carve-up (256B aligned)
  char* ws = (char*)d_ws;
  size_t off = 0;
  auto carve = [&](size_t bytes) -> void* {
    void* p = ws + off; off = (off + bytes + 255) & ~(size_t)255; return p;
  };
  float*          inv     = (float*)carve((size_t)n2 * 4);
  float*          accA    = (float*)carve((size_t)N * 64 * 4);
  float*          accB    = (float*)carve((size_t)N * 64 * 4);
  unsigned short* Y       = (unsigned short*)carve((size_t)N * R * 64 * 2);
  int*            eptr8   = (int*)carve((size_t)(n2 + 1) * 4);
  unsigned*       entry   = (unsigned*)carve((size_t)E * 4);
  int*            bsum    = (int*)carve(1024 * 4);
  int*            glo     = (int*)carve((size_t)(G + 1) * 4);
  float*          partial = (float*)carve((size_t)G * PS * 64 * 4);
  unsigned short* Wb      = (unsigned short*)carve((size_t)(R + 1) * 4096 * 2);
  // dead-before-first-write aliases (same stream ⇒ ordered):
  //   rank[E] (u16) lives only until scatter_edges; accA first written by transform L1.
  //   cnt[n2] (i32) lives only until scan3/invert;  accB first written by transform L2.
  unsigned short* rank = (unsigned short*)accA;
  int*            cnt  = (int*)accB;
  (void)ws_size; (void)n_in;

  const int nb2 = (n2 + SCAN_T * SCAN_E - 1) / (SCAN_T * SCAN_E);

  // ---- CSR build: 1 atomic per edge total ----
  zero_i32<<<(n2 + 255) / 256, 256, 0, stream>>>(cnt, n2);
  count_rank<<<(E + 255) / 256, 256, 0, stream>>>(dstp, etype, cnt, rank, E);
  invert_cnt<<<(n2 + 255) / 256, 256, 0, stream>>>(cnt, inv, n2);
  scan1<<<nb2, SCAN_T, 0, stream>>>(cnt, bsum, n2);
  scan2<<<1, SCAN_T, 0, stream>>>(bsum, eptr8, nb2, n2);
  scan3<<<nb2, SCAN_T, 0, stream>>>(cnt, bsum, eptr8, n2);
  scatter_edges<<<(E + 255) / 256, 256, 0, stream>>>(srcp, dstp, etype, eptr8, rank, entry, E);

  const int tiles = (N + 15) >> 4;
  dim3 tgrid((tiles + 3) / 4, 2);
  const int aggBlocks = (N * 64 + 255) / 256;
  const int wblocks = ((R + 1) * 4096 + 255) / 256;

  // ---- layer 1 ----
  conv_weights<<<wblocks, 256, 0, stream>>>(W1, root1, Wb, R);
  transform_fused<<<tgrid, 256, 0, stream>>>(x, Wb, b1, Y, accA, N, 0);
  edge_agg_csr<<<aggBlocks, 256, 0, stream>>>(Y, eptr8, entry, inv, accA, N);

  // ---- layer 2 (relu fused into transform's input read) ----
  conv_weights<<<wblocks, 256, 0, stream>>>(W2, root2, Wb, R);
  transform_fused<<<tgrid, 256, 0, stream>>>(accA, Wb, b2, Y, accB, N, 1);
  edge_agg_csr<<<aggBlocks, 256, 0, stream>>>(Y, eptr8, entry, inv, accB, N);

  // ---- global mean pool (two-stage, parallel) ----
  glo_bounds<<<1, 128, 0, stream>>>(batch, glo, N, G);
  dim3 pgrid(G, PS);
  pool1<<<pgrid, 256, 0, stream>>>(accB, glo, partial, G);
  pool2<<<G, 64, 0, stream>>>(partial, glo, (float*)d_out, G);
}